// Round 1
// baseline (1129.131 us; speedup 1.0000x reference)
//
#include <hip/hip_runtime.h>
#include <math.h>

#define X_DIM   50
#define SEQ_LEN 230
#define BATCH   16384
#define KTRUE   150      // 3 * X_DIM
#define KPAD    160      // padded K for the GEMM
#define NOUT    1380     // Y_DIM * SEQ_LEN
#define NPAD    1408     // 22 * 64, padded N

typedef float v2f __attribute__((ext_vector_type(2)));

__device__ __forceinline__ v2f vmax2(v2f a, v2f b) {
    v2f r; r.x = fmaxf(a.x, b.x); r.y = fmaxf(a.y, b.y); return r;
}

// ---------------------------------------------------------------------------
// Kernel 1: pad w_out [1380,150] -> wp [1408,160] with zeros
// ---------------------------------------------------------------------------
__global__ __launch_bounds__(256) void prep_w(const float* __restrict__ w,
                                              float* __restrict__ wp) {
    int i = blockIdx.x * 256 + threadIdx.x;     // exact grid
    int n = i / KPAD;
    int k = i - n * KPAD;
    float v = 0.f;
    if (n < NOUT && k < KTRUE) v = w[n * KTRUE + k];
    wp[i] = v;
}

// ---------------------------------------------------------------------------
// Kernel 2: depthwise conv (k=3,6,12) + bias + max, float2: 2 channels/thread.
// Thread (b, cp) handles channels 2cp, 2cp+1; loads are 8 B/lane.
// ---------------------------------------------------------------------------
__global__ __launch_bounds__(256) void conv_max(
    const float* __restrict__ x,   // [B, 230, 50]
    const float* __restrict__ w1, const float* __restrict__ b1,
    const float* __restrict__ w2, const float* __restrict__ b2,
    const float* __restrict__ w3, const float* __restrict__ b3,
    float* __restrict__ flat) {    // [B, KPAD]
    int g = blockIdx.x * 256 + threadIdx.x;     // 0 .. B*25-1 (exact grid)
    int b = g / 25;
    int cp = g - b * 25;
    int c0 = 2 * cp;
    int c1 = c0 + 1;

    const v2f* p = reinterpret_cast<const v2f*>(x + (size_t)b * (SEQ_LEN * X_DIM)) + cp;
    // p[t*25] = channels (c0, c0+1) at time t; 8-byte aligned.

    v2f W1c[3], W2c[6], W3c[12];
#pragma unroll
    for (int i = 0; i < 3; ++i)  { W1c[i].x = w1[c0 * 3 + i];  W1c[i].y = w1[c1 * 3 + i]; }
#pragma unroll
    for (int i = 0; i < 6; ++i)  { W2c[i].x = w2[c0 * 6 + i];  W2c[i].y = w2[c1 * 6 + i]; }
#pragma unroll
    for (int i = 0; i < 12; ++i) { W3c[i].x = w3[c0 * 12 + i]; W3c[i].y = w3[c1 * 12 + i]; }

    v2f m1 = {-1e30f, -1e30f}, m2 = m1, m3 = m1;
    v2f buf[12];

    // ---- prologue: t = 0..11 (window filling; compile-time guards) ----
#pragma unroll
    for (int t = 0; t < 12; ++t) {
        v2f v = p[t * 25];
        buf[t] = v;
        if (t >= 2) {
            v2f s = buf[t - 2] * W1c[0] + buf[t - 1] * W1c[1] + v * W1c[2];
            m1 = vmax2(m1, s);
        }
        if (t >= 5) {
            v2f s = buf[t - 5] * W2c[0];
#pragma unroll
            for (int i = 1; i < 6; ++i) s += buf[t - 5 + i] * W2c[i];
            m2 = vmax2(m2, s);
        }
        if (t == 11) {
            v2f s = buf[0] * W3c[0];
#pragma unroll
            for (int i = 1; i < 12; ++i) s += buf[i] * W3c[i];
            m3 = vmax2(m3, s);
        }
    }

    // ---- main: t = 12..227 in 18 chunks of 12 (ring indices static) ----
    const v2f* q = p + 12 * 25;
#pragma unroll 2
    for (int it = 0; it < 18; ++it) {
#pragma unroll
        for (int j = 0; j < 12; ++j) {
            v2f v = q[j * 25];
            buf[j] = v;
            v2f s1 = buf[(j + 10) % 12] * W1c[0] + buf[(j + 11) % 12] * W1c[1] + v * W1c[2];
            m1 = vmax2(m1, s1);
            v2f s2 = buf[(j + 7) % 12] * W2c[0];
#pragma unroll
            for (int i = 1; i < 6; ++i) s2 += buf[(j + 7 + i) % 12] * W2c[i];
            m2 = vmax2(m2, s2);
            v2f s3 = buf[(j + 1) % 12] * W3c[0];
#pragma unroll
            for (int i = 1; i < 12; ++i) s3 += buf[(j + 1 + i) % 12] * W3c[i];
            m3 = vmax2(m3, s3);
        }
        q += 12 * 25;
    }

    // ---- epilogue: t = 228, 229 (j = 0, 1) ----
#pragma unroll
    for (int j = 0; j < 2; ++j) {
        v2f v = q[j * 25];
        buf[j] = v;
        v2f s1 = buf[(j + 10) % 12] * W1c[0] + buf[(j + 11) % 12] * W1c[1] + v * W1c[2];
        m1 = vmax2(m1, s1);
        v2f s2 = buf[(j + 7) % 12] * W2c[0];
#pragma unroll
        for (int i = 1; i < 6; ++i) s2 += buf[(j + 7 + i) % 12] * W2c[i];
        m2 = vmax2(m2, s2);
        v2f s3 = buf[(j + 1) % 12] * W3c[0];
#pragma unroll
        for (int i = 1; i < 12; ++i) s3 += buf[(j + 1 + i) % 12] * W3c[i];
        m3 = vmax2(m3, s3);
    }

    // bias is position-invariant: max(conv+b) = max(conv)+b
    size_t base = (size_t)b * KPAD + 6 * cp;   // = 3*c0
    flat[base + 0] = m1.x + b1[c0];
    flat[base + 1] = m2.x + b2[c0];
    flat[base + 2] = m3.x + b3[c0];
    flat[base + 3] = m1.y + b1[c1];
    flat[base + 4] = m2.y + b2[c1];
    flat[base + 5] = m3.y + b3[c1];
    if (cp < KPAD - KTRUE) flat[(size_t)b * KPAD + KTRUE + cp] = 0.f;  // zero pad
}

// ---------------------------------------------------------------------------
// Kernel 3: fp32 GEMM  out[b,n] = sum_k flat[b,k] * wp[n,k] + bias[n]
// 128x128 tile, 8x8/thread, BK=16, 256 threads.
// v2 changes: (a) double-buffered LDS, one __syncthreads per K-chunk, global
// loads for chunk k0+1 issued before compute of k0 (latency hidden under
// ~2048 cycles of FMA); (b) per-thread N-columns split as {tn*4, 64+tn*4} so
// Bs ds_read_b128 is 16 lanes at 16 B stride = 2-way bank alias (free) instead
// of 4-way conflict at 32 B stride.
// ---------------------------------------------------------------------------
#define BM 128
#define BN 128
#define BK 16
#define NCHUNK (KPAD / BK)   // 10

__global__ __launch_bounds__(256) void gemm_k(
    const float* __restrict__ A,    // flat [BATCH, KPAD]
    const float* __restrict__ Wp,   // [NPAD, KPAD]
    const float* __restrict__ bias, // [NOUT]
    float* __restrict__ out) {      // [BATCH, NOUT]
    __shared__ float As[2][BK][BM];
    __shared__ float Bs[2][BK][BN];

    int tid = threadIdx.x;
    int bn = blockIdx.x * BN;
    int bm = blockIdx.y * BM;
    int tm = tid >> 4;          // 0..15 -> rows bm + tm*8 .. +7
    int tn = tid & 15;          // 0..15 -> cols {bn+tn*4..+3, bn+64+tn*4..+3}

    int lrow = tid >> 2;        // 0..63
    int lk4  = (tid & 3) * 4;   // 0,4,8,12

    const float* Ap = A  + (size_t)(bm + lrow) * KPAD + lk4;
    const float* Bp = Wp + (size_t)(bn + lrow) * KPAD + lk4;

    float acc[8][8] = {};

    // stage chunk 0 into buffer 0
    {
        float4 a0  = *(const float4*)(Ap);
        float4 a1  = *(const float4*)(Ap + (size_t)64 * KPAD);
        float4 c0  = *(const float4*)(Bp);
        float4 c1  = *(const float4*)(Bp + (size_t)64 * KPAD);
        As[0][lk4 + 0][lrow] = a0.x;  As[0][lk4 + 1][lrow] = a0.y;
        As[0][lk4 + 2][lrow] = a0.z;  As[0][lk4 + 3][lrow] = a0.w;
        As[0][lk4 + 0][lrow + 64] = a1.x;  As[0][lk4 + 1][lrow + 64] = a1.y;
        As[0][lk4 + 2][lrow + 64] = a1.z;  As[0][lk4 + 3][lrow + 64] = a1.w;
        Bs[0][lk4 + 0][lrow] = c0.x;  Bs[0][lk4 + 1][lrow] = c0.y;
        Bs[0][lk4 + 2][lrow] = c0.z;  Bs[0][lk4 + 3][lrow] = c0.w;
        Bs[0][lk4 + 0][lrow + 64] = c1.x;  Bs[0][lk4 + 1][lrow + 64] = c1.y;
        Bs[0][lk4 + 2][lrow + 64] = c1.z;  Bs[0][lk4 + 3][lrow + 64] = c1.w;
        __syncthreads();
    }

    for (int k0 = 0; k0 < NCHUNK; ++k0) {
        int cur = k0 & 1;

        // prefetch next chunk into registers (consumed after compute)
        float4 a0, a1, c0, c1;
        if (k0 < NCHUNK - 1) {
            int off = (k0 + 1) * BK;
            a0 = *(const float4*)(Ap + off);
            a1 = *(const float4*)(Ap + (size_t)64 * KPAD + off);
            c0 = *(const float4*)(Bp + off);
            c1 = *(const float4*)(Bp + (size_t)64 * KPAD + off);
        }

#pragma unroll
        for (int k = 0; k < BK; ++k) {
            float4 av0 = *(const float4*)&As[cur][k][tm * 8];
            float4 av1 = *(const float4*)&As[cur][k][tm * 8 + 4];
            float4 bv0 = *(const float4*)&Bs[cur][k][tn * 4];       // 16B stride: 2-way
            float4 bv1 = *(const float4*)&Bs[cur][k][tn * 4 + 64];  // 16B stride: 2-way
            float a[8]  = {av0.x, av0.y, av0.z, av0.w, av1.x, av1.y, av1.z, av1.w};
            float bf[8] = {bv0.x, bv0.y, bv0.z, bv0.w, bv1.x, bv1.y, bv1.z, bv1.w};
#pragma unroll
            for (int i = 0; i < 8; ++i)
#pragma unroll
                for (int jj = 0; jj < 8; ++jj)
                    acc[i][jj] = fmaf(a[i], bf[jj], acc[i][jj]);
        }

        if (k0 < NCHUNK - 1) {
            int nxt = cur ^ 1;
            As[nxt][lk4 + 0][lrow] = a0.x;  As[nxt][lk4 + 1][lrow] = a0.y;
            As[nxt][lk4 + 2][lrow] = a0.z;  As[nxt][lk4 + 3][lrow] = a0.w;
            As[nxt][lk4 + 0][lrow + 64] = a1.x;  As[nxt][lk4 + 1][lrow + 64] = a1.y;
            As[nxt][lk4 + 2][lrow + 64] = a1.z;  As[nxt][lk4 + 3][lrow + 64] = a1.w;
            Bs[nxt][lk4 + 0][lrow] = c0.x;  Bs[nxt][lk4 + 1][lrow] = c0.y;
            Bs[nxt][lk4 + 2][lrow] = c0.z;  Bs[nxt][lk4 + 3][lrow] = c0.w;
            Bs[nxt][lk4 + 0][lrow + 64] = c1.x;  Bs[nxt][lk4 + 1][lrow + 64] = c1.y;
            Bs[nxt][lk4 + 2][lrow + 64] = c1.z;  Bs[nxt][lk4 + 3][lrow + 64] = c1.w;
            __syncthreads();
        }
    }

    // epilogue: add bias, store two float4 per row.
    // First half column: max n = 1280 + 60 + 3 = 1343 < NOUT -> always valid.
    // Second half needs the guard (max 1407 >= NOUT).
#pragma unroll
    for (int i = 0; i < 8; ++i) {
        size_t m = (size_t)(bm + tm * 8 + i);
        int n0 = bn + tn * 4;
        float4 r0;
        r0.x = acc[i][0] + bias[n0 + 0];
        r0.y = acc[i][1] + bias[n0 + 1];
        r0.z = acc[i][2] + bias[n0 + 2];
        r0.w = acc[i][3] + bias[n0 + 3];
        *(float4*)(out + m * NOUT + n0) = r0;
        int n1 = bn + 64 + tn * 4;
        if (n1 < NOUT) {
            float4 r1;
            r1.x = acc[i][4] + bias[n1 + 0];
            r1.y = acc[i][5] + bias[n1 + 1];
            r1.z = acc[i][6] + bias[n1 + 2];
            r1.w = acc[i][7] + bias[n1 + 3];
            *(float4*)(out + m * NOUT + n1) = r1;
        }
    }
}

// ---------------------------------------------------------------------------
extern "C" void kernel_launch(void* const* d_in, const int* in_sizes, int n_in,
                              void* d_out, int out_size, void* d_ws, size_t ws_size,
                              hipStream_t stream) {
    const float* seq   = (const float*)d_in[0];
    const float* w1    = (const float*)d_in[1];
    const float* b1    = (const float*)d_in[2];
    const float* w2    = (const float*)d_in[3];
    const float* b2    = (const float*)d_in[4];
    const float* w3    = (const float*)d_in[5];
    const float* b3    = (const float*)d_in[6];
    const float* w_out = (const float*)d_in[7];
    const float* b_out = (const float*)d_in[8];
    float* out = (float*)d_out;

    // workspace layout: flat [BATCH*KPAD] fp32, then wp [NPAD*KPAD] fp32
    float* flat = (float*)d_ws;
    float* wp   = flat + (size_t)BATCH * KPAD;

    prep_w<<<(NPAD * KPAD) / 256, 256, 0, stream>>>(w_out, wp);
    conv_max<<<(BATCH * 25) / 256, 256, 0, stream>>>(
        seq, w1, b1, w2, b2, w3, b3, flat);
    gemm_k<<<dim3(NPAD / BN, BATCH / BM), 256, 0, stream>>>(flat, wp, b_out, out);
}